// Round 11
// baseline (70838.708 us; speedup 1.0000x reference)
//
#include <hip/hip_runtime.h>

#define BB 16
#define SS 128
#define TT 128
#define EE 512
#define HH 512
#define DD 1024
#define VO 10000

typedef _Float16 half8_t __attribute__((ext_vector_type(8)));

#define FMA4(A, W, X)              \
  A = fmaf((W).x, (X).x, A);       \
  A = fmaf((W).y, (X).y, A);       \
  A = fmaf((W).z, (X).z, A);       \
  A = fmaf((W).w, (X).w, A)

__device__ __forceinline__ float wred(float s) {
#pragma unroll
  for (int off = 32; off >= 1; off >>= 1) s += __shfl_xor(s, off, 64);
  return s;
}
__device__ __forceinline__ float sigm(float x) { return 1.f / (1.f + expf(-x)); }

__device__ __forceinline__ void stv(float* p, float v) {
  __hip_atomic_store(p, v, __ATOMIC_RELAXED, __HIP_MEMORY_SCOPE_AGENT);
}

// ---- grid barrier v2: flag-scan, relaxed-only (validated R7-R10) ----
__device__ __forceinline__ void gbar2(unsigned* bar, int lb, int nblk, unsigned target) {
  asm volatile("s_waitcnt vmcnt(0) lgkmcnt(0)" ::: "memory");
  __syncthreads();
  if (threadIdx.x == 0)
    __hip_atomic_store(bar + lb * 16, target, __ATOMIC_RELAXED, __HIP_MEMORY_SCOPE_AGENT);
  if (lb == 0) {
    for (int i = threadIdx.x; i < nblk; i += blockDim.x)
      while (__hip_atomic_load(bar + i * 16, __ATOMIC_RELAXED, __HIP_MEMORY_SCOPE_AGENT) <
             target)
        __builtin_amdgcn_s_sleep(1);
    __syncthreads();
    if (threadIdx.x == 0)
      __hip_atomic_store(bar + 8192, target, __ATOMIC_RELAXED, __HIP_MEMORY_SCOPE_AGENT);
  }
  if (threadIdx.x == 0)
    while (__hip_atomic_load(bar + 8192, __ATOMIC_RELAXED, __HIP_MEMORY_SCOPE_AGENT) <
           target)
      __builtin_amdgcn_s_sleep(1);
  __syncthreads();
}

// ---- fp32 -> fp16 conversion (8 elems/thread) ----
__global__ void f2h_k(const float* __restrict__ src, _Float16* __restrict__ dst, int n8) {
  const int i = blockIdx.x * blockDim.x + threadIdx.x;
  if (i < n8) {
    const float4 a = *(const float4*)&src[i * 8];
    const float4 b = *(const float4*)&src[i * 8 + 4];
    half8_t h;
    h[0] = a.x; h[1] = a.y; h[2] = a.z; h[3] = a.w;
    h[4] = b.x; h[5] = b.y; h[6] = b.z; h[7] = b.w;
    *(half8_t*)&dst[i * 8] = h;
  }
}

// ---- embedding gather (padding_idx=0 -> zeros), out layout [Sn][B][E] ----
__global__ void gather_k(const int* __restrict__ idx, const float* __restrict__ emb,
                         float* __restrict__ out, int Sn) {
  const int s = blockIdx.x, b = blockIdx.y, tid = threadIdx.x;
  const int id = idx[b * Sn + s];
  float4 v = make_float4(0.f, 0.f, 0.f, 0.f);
  if (id != 0) v = ((const float4*)(emb + (size_t)id * EE))[tid];
  ((float4*)(out + ((size_t)s * BB + b) * EE))[tid] = v;
}

// ---- G[z][n][m] = sum_k X[m,k]*W[z,n,k]  (x-part gate GEMMs, float4) ----
template <int K>
__global__ void gemv16b_k(const float* __restrict__ X, int ldx,
                          const float* __restrict__ W, int ldw,
                          float* __restrict__ G, int M, size_t wz, size_t gz) {
  const int lane = threadIdx.x & 63;
  const int n = blockIdx.x * 4 + (threadIdx.x >> 6);
  const int mg = blockIdx.y;
  const int z = blockIdx.z;
  const float* Xr = X + (size_t)mg * 16 * ldx;
  const float* Wn = W + (size_t)z * wz + (size_t)n * ldw;
  float acc[16];
#pragma unroll
  for (int j = 0; j < 16; ++j) acc[j] = 0.f;
#pragma unroll
  for (int it = 0; it < K / 256; ++it) {
    const int k = it * 256 + lane * 4;
    const float4 w4 = *(const float4*)&Wn[k];
#pragma unroll
    for (int j = 0; j < 16; ++j) {
      const float4 xv = *(const float4*)&Xr[(size_t)j * ldx + k];
      FMA4(acc[j], w4, xv);
    }
  }
#pragma unroll
  for (int j = 0; j < 16; ++j) acc[j] = wred(acc[j]);
  float sel = 0.f;
#pragma unroll
  for (int j = 0; j < 16; ++j)
    if (lane == j) sel = acc[j];
  if (lane < 16) G[(size_t)z * gz + (size_t)n * M + mg * 16 + lane] = sel;
}

// ---- persistent encoder: 256 blocks x 512 thr (unchanged from R9) ----
__global__ __launch_bounds__(512, 4) void enc_mega7_k(
    const float* __restrict__ gx, const float* __restrict__ whh,
    const float* __restrict__ bias, float* __restrict__ h_all,
    float* __restrict__ seq, int seq_ts, int seq_bs, unsigned* __restrict__ barbase) {
  const int tid = threadIdx.x, lane = tid & 63, lw = tid >> 6;
  const int dir = blockIdx.x >> 7;
  const int lb = blockIdx.x & 127;
  const int w2 = lb * 8 + lw;
  const int d = w2 >> 1, bq = w2 & 1;
  unsigned* bar = barbase + dir * 16384;

  __shared__ float hs[16][512];

  float wr[4][8];
  const float* wsrc = whh + (size_t)dir * (4 * HH * HH);
#pragma unroll
  for (int g = 0; g < 4; ++g)
#pragma unroll
    for (int j = 0; j < 8; ++j)
      wr[g][j] = wsrc[(size_t)(g * HH + d) * HH + j * 64 + lane];
  float bv[4];
#pragma unroll
  for (int g = 0; g < 4; ++g) bv[g] = bias[dir * 4 * HH + g * HH + d];
  const float* gxz = gx + (size_t)dir * ((size_t)4 * HH * 2048);
  float creg = 0.f;
  unsigned bt = 0;

  for (int t = 0; t < SS; ++t) {
    const int idx = dir ? (SS - 1 - t) : t;
    const float* hp = h_all + ((size_t)t * 2 + dir) * (BB * HH);
    for (int i = tid; i < BB * HH / 4; i += 512)
      *(float4*)&((float*)hs)[i * 4] = *(const float4*)&hp[i * 4];
    __syncthreads();
    float acc[4][8];
#pragma unroll
    for (int g = 0; g < 4; ++g)
#pragma unroll
      for (int j = 0; j < 8; ++j) acc[g][j] = 0.f;
#pragma unroll
    for (int kb = 0; kb < 8; ++kb) {
      const int k = kb * 64 + lane;
#pragma unroll
      for (int j = 0; j < 8; ++j) {
        const float xv = hs[bq * 8 + j][k];
#pragma unroll
        for (int g = 0; g < 4; ++g) acc[g][j] = fmaf(wr[g][kb], xv, acc[g][j]);
      }
    }
#pragma unroll
    for (int g = 0; g < 4; ++g)
#pragma unroll
      for (int j = 0; j < 8; ++j) acc[g][j] = wred(acc[g][j]);
    float s0 = 0.f, s1 = 0.f, s2 = 0.f, s3 = 0.f;
#pragma unroll
    for (int j = 0; j < 8; ++j)
      if (lane == j) { s0 = acc[0][j]; s1 = acc[1][j]; s2 = acc[2][j]; s3 = acc[3][j]; }
    if (lane < 8) {
      const int b = bq * 8 + lane;
      const int m = idx * 16 + b;
      const float gi = sigm(s0 + bv[0] + gxz[(size_t)(0 * HH + d) * 2048 + m]);
      const float gf = sigm(s1 + bv[1] + gxz[(size_t)(1 * HH + d) * 2048 + m]);
      const float gg = tanhf(s2 + bv[2] + gxz[(size_t)(2 * HH + d) * 2048 + m]);
      const float go = sigm(s3 + bv[3] + gxz[(size_t)(3 * HH + d) * 2048 + m]);
      const float cn = gf * creg + gi * gg;
      creg = cn;
      const float hv = go * tanhf(cn);
      stv(h_all + ((size_t)(t + 1) * 2 + dir) * (BB * HH) + b * HH + d, hv);
      seq[(size_t)idx * seq_ts + (size_t)b * seq_bs + dir * HH + d] = hv;
    }
    gbar2(bar, lb, 128, ++bt);
  }
}

// dot helper: 2 fp16 weight rows x 8 batches over one 512-elem K chunk
__device__ __forceinline__ void dot2x8(const _Float16* __restrict__ wA,
                                       const _Float16* __restrict__ wB,
                                       const float* __restrict__ xbase, int xstride,
                                       int lane, float (&acc)[2][8]) {
  const half8_t a8 = *(const half8_t*)&wA[lane * 8];
  const half8_t b8 = *(const half8_t*)&wB[lane * 8];
  float af[8], bf[8];
#pragma unroll
  for (int e = 0; e < 8; ++e) { af[e] = (float)a8[e]; bf[e] = (float)b8[e]; }
#pragma unroll
  for (int b = 0; b < 8; ++b) {
    const float* xp = xbase + (size_t)b * xstride + lane * 8;
    const float4 x0 = *(const float4*)xp;
    const float4 x1 = *(const float4*)(xp + 4);
    acc[0][b] = fmaf(af[0], x0.x, acc[0][b]); acc[1][b] = fmaf(bf[0], x0.x, acc[1][b]);
    acc[0][b] = fmaf(af[1], x0.y, acc[0][b]); acc[1][b] = fmaf(bf[1], x0.y, acc[1][b]);
    acc[0][b] = fmaf(af[2], x0.z, acc[0][b]); acc[1][b] = fmaf(bf[2], x0.z, acc[1][b]);
    acc[0][b] = fmaf(af[3], x0.w, acc[0][b]); acc[1][b] = fmaf(bf[3], x0.w, acc[1][b]);
    acc[0][b] = fmaf(af[4], x1.x, acc[0][b]); acc[1][b] = fmaf(bf[4], x1.x, acc[1][b]);
    acc[0][b] = fmaf(af[5], x1.y, acc[0][b]); acc[1][b] = fmaf(bf[5], x1.y, acc[1][b]);
    acc[0][b] = fmaf(af[6], x1.z, acc[0][b]); acc[1][b] = fmaf(bf[6], x1.z, acc[1][b]);
    acc[0][b] = fmaf(af[7], x1.w, acc[0][b]); acc[1][b] = fmaf(bf[7], x1.w, acc[1][b]);
  }
}

// reduce acc[2][8] across lanes and write to xch[gate][kh][batch]
__device__ __forceinline__ void combine2x8(float (&acc)[2][8], float (*xch)[4][2][16],
                                           int dl, int rp, int bh, int kh, int lane) {
#pragma unroll
  for (int r = 0; r < 2; ++r)
#pragma unroll
    for (int b = 0; b < 8; ++b) acc[r][b] = wred(acc[r][b]);
  float sel = 0.f;
#pragma unroll
  for (int j = 0; j < 16; ++j)
    if (lane == j) sel = acc[j >> 3][j & 7];
  if (lane < 16) xch[dl][rp * 2 + (lane >> 3)][kh][bh * 8 + (lane & 7)] = sel;
}

// ---- persistent decoder v9: 512 blocks x 1024 thr (2/CU, 32 waves/CU),
// fp16 weights, wave = 2 gate-rows x 8 batches x K-half ----
__global__ __launch_bounds__(1024, 8) void dec_mega9_k(
    const float* __restrict__ gs_emb, const float* __restrict__ encWe,
    const float* __restrict__ enc_out, const _Float16* __restrict__ aw16,
    const float* __restrict__ attn_b, const float* __restrict__ attn_v,
    const _Float16* __restrict__ w16i0, const _Float16* __restrict__ w16h0,
    const float* __restrict__ b0, const _Float16* __restrict__ w16i1,
    const _Float16* __restrict__ w16h1, const float* __restrict__ b1,
    const float* __restrict__ zeros, float* __restrict__ h0_all,
    float* __restrict__ h1_all, float* __restrict__ c1_all, float* __restrict__ wtd_all,
    float* __restrict__ qW_all, float* __restrict__ scores_all,
    unsigned* __restrict__ bar) {
  const int tid = threadIdx.x, lane = tid & 63, lw = tid >> 6;
  const int blk = blockIdx.x;
  const int dl = lw >> 3;            // 0/1: which d of the block's pair
  const int d = blk * 2 + dl;
  const int rp = (lw >> 2) & 1;      // row-pair: gates {0,1} or {2,3}
  const int bh = (lw >> 1) & 1;      // batch half
  const int kh = lw & 1;             // K half
  const int b_att = blk >> 5, sq = blk & 31;  // attention mapping

  __shared__ float xch[2][4][2][16];  // [dl][gate][kh][batch]
  __shared__ float qch[2][2][16];     // [dl][kh][batch]
  __shared__ float sch[4][2];         // [sidx][kh]
  __shared__ float sco[SS];
  __shared__ float sred[32][33];

  const int r0 = rp * 2, r1 = rp * 2 + 1;
  const _Float16* wi0A = w16i0 + (size_t)(r0 * DD + d) * 1536;
  const _Float16* wi0B = w16i0 + (size_t)(r1 * DD + d) * 1536;
  const _Float16* wh0A = w16h0 + (size_t)(r0 * DD + d) * 1024;
  const _Float16* wh0B = w16h0 + (size_t)(r1 * DD + d) * 1024;
  const _Float16* wi1A = w16i1 + (size_t)(r0 * DD + d) * 1024;
  const _Float16* wi1B = w16i1 + (size_t)(r1 * DD + d) * 1024;
  const _Float16* wh1A = w16h1 + (size_t)(r0 * DD + d) * 1024;
  const _Float16* wh1B = w16h1 + (size_t)(r1 * DD + d) * 1024;
  float c0 = 0.f, c1 = 0.f;
  unsigned bt = 0;
  const bool owner = (lw == dl * 8);  // one owner wave per d

  // ---- prime layer 0: zero input & state -> gates = biases ----
  if (owner && lane < 16) {
    const float cn = sigm(b0[d]) * tanhf(b0[2 * DD + d]);
    c0 = cn;
    stv(h0_all + lane * DD + d, sigm(b0[3 * DD + d]) * tanhf(cn));
  }
  gbar2(bar, blk, 512, ++bt);
  // ---- prime layer 1: wih1 . h0_all[0]  (h1prev = zeros) ----
  {
    float acc[2][8];
#pragma unroll
    for (int r = 0; r < 2; ++r)
#pragma unroll
      for (int b = 0; b < 8; ++b) acc[r][b] = 0.f;
    const float* xb = (kh == 0) ? h0_all : zeros;  // kh0: h0 chunks, kh1: zeros
#pragma unroll
    for (int c = 0; c < 2; ++c)
      dot2x8(wi1A + (kh * 1024 + c * 512) % 1024 + (kh ? 0 : c * 512),
             wi1B + (kh ? c * 512 : c * 512), xb + (kh ? 0 : c * 512) + (kh ? c * 512 : 0),
             1024, lane, acc);
    // note: for kh==1 the x is zeros so the (arbitrary) weight segment contributes 0
    combine2x8(acc, xch, dl, rp, bh, kh, lane);
    __syncthreads();
    if (owner && lane < 16) {
      float gv[4];
#pragma unroll
      for (int g = 0; g < 4; ++g)
        gv[g] = xch[dl][g][0][lane] + xch[dl][g][1][lane] + b1[g * DD + d];
      const float cn = sigm(gv[0]) * tanhf(gv[2]);
      c1 = cn;
      stv(c1_all + lane * DD + d, cn);
      stv(h1_all + lane * DD + d, sigm(gv[3]) * tanhf(cn));
    }
    __syncthreads();
  }
  gbar2(bar, blk, 512, ++bt);

  for (int t = 0; t < TT; ++t) {
    // ===== qW: wave = (d, batch-quad bq, K-half); fp16 attn_w row =====
    {
      const int bq = (lw >> 1) & 3;  // reuse rp,bh bits as batch-quad
      const float* cb = c1_all + (size_t)t * (BB * DD);
      const half8_t w8 = *(const half8_t*)&aw16[(size_t)d * 2048 + kh * 512 + lane * 8];
      float wf[8];
#pragma unroll
      for (int e = 0; e < 8; ++e) wf[e] = (float)w8[e];
      float acc[4] = {0.f, 0.f, 0.f, 0.f};
#pragma unroll
      for (int b = 0; b < 4; ++b) {
        const float* xp = cb + (bq * 4 + b) * DD + kh * 512 + lane * 8;
        const float4 x0 = *(const float4*)xp;
        const float4 x1 = *(const float4*)(xp + 4);
        acc[b] = fmaf(wf[0], x0.x, acc[b]); acc[b] = fmaf(wf[1], x0.y, acc[b]);
        acc[b] = fmaf(wf[2], x0.z, acc[b]); acc[b] = fmaf(wf[3], x0.w, acc[b]);
        acc[b] = fmaf(wf[4], x1.x, acc[b]); acc[b] = fmaf(wf[5], x1.y, acc[b]);
        acc[b] = fmaf(wf[6], x1.z, acc[b]); acc[b] = fmaf(wf[7], x1.w, acc[b]);
      }
#pragma unroll
      for (int b = 0; b < 4; ++b) acc[b] = wred(acc[b]);
      float sel = 0.f;
#pragma unroll
      for (int b = 0; b < 4; ++b)
        if (lane == b) sel = acc[b];
      if (lane < 4) qch[dl][kh][bq * 4 + lane] = sel;
      __syncthreads();
      if (owner && lane < 16)
        stv(qW_all + (size_t)t * (BB * DD) + lane * DD + d,
            qch[dl][0][lane] + qch[dl][1][lane] + attn_b[d]);
      __syncthreads();
    }
    gbar2(bar, blk, 512, ++bt);
    // ===== scores: block (b_att, sq); waves lw<8: s = sq*4 + (lw>>1), K-half =====
    if (lw < 8) {
      const int sidx = lw >> 1;
      const int s = sq * 4 + sidx;
      const int k0 = (lw & 1) * 512 + lane * 8;
      const float* ew = encWe + ((size_t)(b_att * SS + s)) * DD + k0;
      const float* qb = qW_all + (size_t)t * (BB * DD) + b_att * DD + k0;
      const float* vv = attn_v + k0;
      float a = 0.f;
#pragma unroll
      for (int h = 0; h < 2; ++h) {
        const float4 e4 = *(const float4*)(ew + h * 4);
        const float4 q4 = *(const float4*)(qb + h * 4);
        const float4 v4 = *(const float4*)(vv + h * 4);
        a += v4.x * tanhf(q4.x + e4.x) + v4.y * tanhf(q4.y + e4.y) +
             v4.z * tanhf(q4.z + e4.z) + v4.w * tanhf(q4.w + e4.w);
      }
      a = wred(a);
      if (lane == 0) sch[sidx][lw & 1] = a;
    }
    __syncthreads();
    if (tid < 4)
      stv(scores_all + (size_t)t * (BB * SS) + b_att * SS + sq * 4 + tid,
          sch[tid][0] + sch[tid][1]);
    gbar2(bar, blk, 512, ++bt);
    // ===== softmax + weighted: block (b_att, shard sq) -> cols sq*32..+31 =====
    {
      if (tid < SS) sco[tid] = scores_all[(size_t)t * (BB * SS) + b_att * SS + tid];
      __syncthreads();
      float m = -1e30f;
      for (int s = 0; s < SS; ++s) m = fmaxf(m, sco[s]);
      __syncthreads();
      if (tid < SS) sco[tid] = expf(sco[tid] - m);
      __syncthreads();
      float sum = 0.f;
      for (int s = 0; s < SS; ++s) sum += sco[s];
      const float inv = 1.f / sum;
      const int col = tid & 31, sg = tid >> 5;  // 32 s-groups of 4
      float p = 0.f;
#pragma unroll
      for (int i = 0; i < 4; ++i) {
        const int s = sg * 4 + i;
        p += sco[s] * enc_out[((size_t)(b_att * SS + s)) * DD + sq * 32 + col];
      }
      sred[sg][col] = p;
      __syncthreads();
      if (tid < 32) {
        float a2 = 0.f;
#pragma unroll
        for (int i = 0; i < 32; ++i) a2 += sred[i][tid];
        stv(wtd_all + (size_t)t * (BB * DD) + b_att * DD + sq * 32 + tid, a2 * inv);
      }
    }
    gbar2(bar, blk, 512, ++bt);
    // ===== dec layer 0: kh0 = wtd(2 chunks)+emb(1), kh1 = h0prev(2 chunks) =====
    {
      float acc[2][8];
#pragma unroll
      for (int r = 0; r < 2; ++r)
#pragma unroll
        for (int b = 0; b < 8; ++b) acc[r][b] = 0.f;
      if (kh == 0) {
        const float* xw = wtd_all + (size_t)t * (BB * DD) + bh * 8 * DD;
        const float* em = (t ? gs_emb + (size_t)(t - 1) * (BB * EE) : zeros) + bh * 8 * EE;
        dot2x8(wi0A, wi0B, xw, DD, lane, acc);
        dot2x8(wi0A + 512, wi0B + 512, xw + 512, DD, lane, acc);
        dot2x8(wi0A + 1024, wi0B + 1024, em, EE, lane, acc);
      } else {
        const float* hp = h0_all + (size_t)t * (BB * DD) + bh * 8 * DD;
        dot2x8(wh0A, wh0B, hp, DD, lane, acc);
        dot2x8(wh0A + 512, wh0B + 512, hp + 512, DD, lane, acc);
      }
      combine2x8(acc, xch, dl, rp, bh, kh, lane);
      __syncthreads();
      if (owner && lane < 16) {
        float gv[4];
#pragma unroll
        for (int g = 0; g < 4; ++g)
          gv[g] = xch[dl][g][0][lane] + xch[dl][g][1][lane] + b0[g * DD + d];
        const float cn = sigm(gv[1]) * c0 + sigm(gv[0]) * tanhf(gv[2]);
        c0 = cn;
        stv(h0_all + (size_t)(t + 1) * (BB * DD) + lane * DD + d,
            sigm(gv[3]) * tanhf(cn));
      }
      __syncthreads();
    }
    gbar2(bar, blk, 512, ++bt);
    // ===== dec layer 1: kh0 = h0new(2 chunks), kh1 = h1prev(2 chunks) =====
    {
      float acc[2][8];
#pragma unroll
      for (int r = 0; r < 2; ++r)
#pragma unroll
        for (int b = 0; b < 8; ++b) acc[r][b] = 0.f;
      if (kh == 0) {
        const float* h0 = h0_all + (size_t)(t + 1) * (BB * DD) + bh * 8 * DD;
        dot2x8(wi1A, wi1B, h0, DD, lane, acc);
        dot2x8(wi1A + 512, wi1B + 512, h0 + 512, DD, lane, acc);
      } else {
        const float* h1p = h1_all + (size_t)t * (BB * DD) + bh * 8 * DD;
        dot2x8(wh1A, wh1B, h1p, DD, lane, acc);
        dot2x8(wh1A + 512, wh1B + 512, h1p + 512, DD, lane, acc);
      }
      combine2x8(acc, xch, dl, rp, bh, kh, lane);
      __syncthreads();
      if (owner && lane < 16) {
        float gv[4];
#pragma unroll
        for (int g = 0; g < 4; ++g)
          gv[g] = xch[dl][g][0][lane] + xch[dl][g][1][lane] + b1[g * DD + d];
        const float cn = sigm(gv[1]) * c1 + sigm(gv[0]) * tanhf(gv[2]);
        c1 = cn;
        stv(c1_all + (size_t)(t + 1) * (BB * DD) + lane * DD + d, cn);
        stv(h1_all + (size_t)(t + 1) * (BB * DD) + lane * DD + d,
            sigm(gv[3]) * tanhf(cn));
      }
      __syncthreads();
    }
    gbar2(bar, blk, 512, ++bt);
  }
}

// ---- encWe[m][n] = sum_k enc_out[m][k]*attn_w[n][1024+k], LDS-staged, float4 ----
__global__ __launch_bounds__(512) void encwe2_k(const float* __restrict__ enc_out,
                                                const float* __restrict__ attn_w,
                                                float* __restrict__ encWe) {
  const int tid = threadIdx.x, lane = tid & 63, lw = tid >> 6;
  const int mg = blockIdx.x;
  const int nq = blockIdx.y;
  __shared__ float xsl[16][1024];
  for (int i = tid; i < 16 * 1024 / 4; i += 512)
    *(float4*)&((float*)xsl)[i * 4] =
        *(const float4*)&enc_out[(size_t)mg * 16 * 1024 + i * 4];
  __syncthreads();
#pragma unroll 1
  for (int nn = 0; nn < 8; ++nn) {
    const int n = nq * 64 + lw * 8 + nn;
    float acc[16];
#pragma unroll
    for (int j = 0; j < 16; ++j) acc[j] = 0.f;
#pragma unroll
    for (int it = 0; it < 4; ++it) {
      const int k = it * 256 + lane * 4;
      const float4 w4 = *(const float4*)&attn_w[(size_t)n * 2048 + 1024 + k];
#pragma unroll
      for (int j = 0; j < 16; ++j) {
        const float4 xv = *(const float4*)&xsl[j][k];
        FMA4(acc[j], w4, xv);
      }
    }
#pragma unroll
    for (int j = 0; j < 16; ++j) acc[j] = wred(acc[j]);
    float sel = 0.f;
#pragma unroll
    for (int j = 0; j < 16; ++j)
      if (lane == j) sel = acc[j];
    if (lane < 16) encWe[((size_t)mg * 16 + lane) * 1024 + n] = sel;
  }
}

// ---- logits (fp16 out_w): block = (t, 80 o-rows); h1[t] in LDS ----
__global__ __launch_bounds__(1024, 2) void logits3_k(const float* __restrict__ h1all,
                                                     const _Float16* __restrict__ ow16,
                                                     const float* __restrict__ out_b,
                                                     float* __restrict__ out) {
  const int tid = threadIdx.x, lane = tid & 63, lw = tid >> 6;
  const int t = blockIdx.x;
  const int oq = blockIdx.y;  // 0..124
  __shared__ float hs[16][1024];
  const float* h1 = h1all + (size_t)t * (BB * DD);
  for (int i = tid; i < BB * DD / 4; i += 1024)
    *(float4*)&((float*)hs)[i * 4] = *(const float4*)&h1[i * 4];
  __syncthreads();
  const int obase = oq * 80 + lw * 5;
#pragma unroll
  for (int p = 0; p < 3; ++p) {
    const int nr = (p < 2) ? 2 : 1;
    const int o0 = obase + p * 2;
    float accA[16], accB[16];
#pragma unroll
    for (int b = 0; b < 16; ++b) { accA[b] = 0.f; accB[b] = 0.f; }
    const _Float16* wr0 = ow16 + (size_t)o0 * DD;
    const _Float16* wr1 = wr0 + DD;
#pragma unroll
    for (int it = 0; it < 2; ++it) {
      const int k = it * 512 + lane * 8;
      const half8_t wa8 = *(const half8_t*)&wr0[k];
      half8_t wb8 = wa8;
      if (nr == 2) wb8 = *(const half8_t*)&wr1[k];
      float wa[8], wb[8];
#pragma unroll
      for (int e = 0; e < 8; ++e) { wa[e] = (float)wa8[e]; wb[e] = (float)wb8[e]; }
#pragma unroll
      for (int b = 0; b < 16; ++b) {
        const float4 x0 = *(const float4*)&hs[b][k];
        const float4 x1 = *(const float4*)&hs[b][k + 4];
        accA[b] = fmaf(wa[0], x0.x, accA[b]); accA[b] = fmaf(wa[1], x0.y, accA[b]);
        accA[b] = fmaf(wa[2], x0.z, accA[b]); accA[b] = fmaf(wa[3], x0.w, accA[b]);
        accA[b] = fmaf(wa[4], x1.x, accA[b]); accA[b] = fmaf(wa[5], x1.y, accA[b]);
        accA[b] = fmaf(wa[6], x1.z, accA[b]); accA[b] = fmaf(wa[7], x1.w, accA[b]);
        if (nr == 2) {
          accB[b] = fmaf(wb[0], x0.x, accB[b]); accB[b] = fmaf(wb[1], x0.y, accB[b]);
          accB[b] = fmaf(wb[2], x0.z, accB[b]); accB[b] = fmaf(wb[3], x0.w, accB[b]);
          accB[b] = fmaf(wb[4], x1.x, accB[b]); accB[b] = fmaf(wb[5], x1.y, accB[b]);
          accB[b] = fmaf(wb[6], x1.z, accB[b]); accB[b] = fmaf(wb[7], x1.w, accB[b]);
        }
      }
    }
#pragma unroll
    for (int b = 0; b < 16; ++b) {
      accA[b] = wred(accA[b]);
      if (nr == 2) accB[b] = wred(accB[b]);
    }
    float sA = 0.f, sB = 0.f;
#pragma unroll
    for (int b = 0; b < 16; ++b)
      if (lane == b) { sA = accA[b]; sB = accB[b]; }
    if (lane < 16) {
      out[(size_t)lane * TT * VO + (size_t)t * VO + o0] = sA + out_b[o0];
      if (nr == 2) out[(size_t)lane * TT * VO + (size_t)t * VO + o0 + 1] = sB + out_b[o0 + 1];
    }
  }
}

extern "C" void kernel_launch(void* const* d_in, const int* in_sizes, int n_in,
                              void* d_out, int out_size, void* d_ws, size_t ws_size,
                              hipStream_t stream) {
  const int* x = (const int*)d_in[0];
  const int* gs = (const int*)d_in[1];
  const float* in_emb = (const float*)d_in[2];
  const float* out_emb = (const float*)d_in[3];
  const float* ewih0 = (const float*)d_in[4];
  const float* ewhh0 = (const float*)d_in[5];
  const float* eb0 = (const float*)d_in[6];
  const float* ewih1 = (const float*)d_in[7];
  const float* ewhh1 = (const float*)d_in[8];
  const float* eb1 = (const float*)d_in[9];
  const float* dwih0 = (const float*)d_in[10];
  const float* dwhh0 = (const float*)d_in[11];
  const float* db0 = (const float*)d_in[12];
  const float* dwih1 = (const float*)d_in[13];
  const float* dwhh1 = (const float*)d_in[14];
  const float* db1 = (const float*)d_in[15];
  const float* attn_w = (const float*)d_in[16];
  const float* attn_b = (const float*)d_in[17];
  const float* attn_v = (const float*)d_in[18];
  const float* out_w = (const float*)d_in[19];
  const float* out_b = (const float*)d_in[20];
  float* out = (float*)d_out;

  float* ws = (float*)d_ws;
  size_t off = 0;
  auto alloc = [&](size_t n) { float* p = ws + off; off += n; return p; };
  // ---- memset region: 5 barrier domains + zeros + enc h_all slot-0s ----
  unsigned* bar = (unsigned*)alloc(5 * 16384);  // encL0 d0/d1, encL1 d0/d1, dec
  float* zeros = alloc(BB * DD);
  float* ehA = alloc((size_t)(SS + 1) * 2 * BB * HH);
  float* ehB = alloc(2 * BB * HH);
  const size_t state_n = off;
  alloc((size_t)SS * 2 * BB * HH);  // enc L1 h_all slots 1..128 (contiguous w/ ehB)
  // ---- fp16 weight copies ----
  _Float16* w16i0 = (_Float16*)alloc(4096 * 1536 / 2);
  _Float16* w16h0 = (_Float16*)alloc(4096 * 1024 / 2);
  _Float16* w16i1 = (_Float16*)alloc(4096 * 1024 / 2);
  _Float16* w16h1 = (_Float16*)alloc(4096 * 1024 / 2);
  _Float16* aw16 = (_Float16*)alloc(1024 * 2048 / 2);
  _Float16* ow16 = (_Float16*)alloc((size_t)VO * DD / 2);
  // ---- in-kernel write-once / fully-written buffers ----
  float* h0_all = alloc((size_t)(TT + 1) * BB * DD);
  float* h1_all = alloc((size_t)(TT + 1) * BB * DD);
  float* c1_all = alloc((size_t)(TT + 1) * BB * DD);
  float* wtd_all = alloc((size_t)TT * BB * DD);
  float* qW_all = alloc((size_t)TT * BB * DD);
  float* scores_all = alloc((size_t)TT * BB * SS);
  float* xs_emb = alloc((size_t)SS * BB * EE);
  float* gs_emb = alloc((size_t)TT * BB * EE);
  float* l0 = alloc((size_t)SS * BB * (2 * HH));
  float* enc_out = alloc((size_t)BB * SS * (2 * HH));
  float* encWe = alloc((size_t)BB * SS * DD);
  float* gxA = alloc(2ull * 2048ull * 2048ull);
  (void)ws_size; (void)in_sizes; (void)n_in; (void)out_size;

  hipMemsetAsync(d_ws, 0, state_n * sizeof(float), stream);

  // fp16 weight conversion (parallel, independent)
  f2h_k<<<(4096 * 1536 / 8 + 255) / 256, 256, 0, stream>>>(dwih0, w16i0, 4096 * 1536 / 8);
  f2h_k<<<(4096 * 1024 / 8 + 255) / 256, 256, 0, stream>>>(dwhh0, w16h0, 4096 * 1024 / 8);
  f2h_k<<<(4096 * 1024 / 8 + 255) / 256, 256, 0, stream>>>(dwih1, w16i1, 4096 * 1024 / 8);
  f2h_k<<<(4096 * 1024 / 8 + 255) / 256, 256, 0, stream>>>(dwhh1, w16h1, 4096 * 1024 / 8);
  f2h_k<<<(1024 * 2048 / 8 + 255) / 256, 256, 0, stream>>>(attn_w, aw16, 1024 * 2048 / 8);
  f2h_k<<<(VO * DD / 8 + 255) / 256, 256, 0, stream>>>(out_w, ow16, VO * DD / 8);

  gather_k<<<dim3(SS, BB), 128, 0, stream>>>(x, in_emb, xs_emb, SS);
  gather_k<<<dim3(TT, BB), 128, 0, stream>>>(gs, out_emb, gs_emb, TT);

  // encoder layer 0: parallel x-part, then persistent recurrence
  gemv16b_k<EE><<<dim3(512, 128, 2), 256, 0, stream>>>(
      xs_emb, EE, ewih0, EE, gxA, 2048, (size_t)4 * HH * EE, 2048ull * 2048ull);
  enc_mega7_k<<<256, 512, 0, stream>>>(gxA, ewhh0, eb0, ehA, l0, BB * 2 * HH, 2 * HH, bar);
  // encoder layer 1
  gemv16b_k<2 * HH><<<dim3(512, 128, 2), 256, 0, stream>>>(
      l0, 2 * HH, ewih1, 2 * HH, gxA, 2048, (size_t)4 * HH * 2 * HH, 2048ull * 2048ull);
  enc_mega7_k<<<256, 512, 0, stream>>>(gxA, ewhh1, eb1, ehB, enc_out, 2 * HH, SS * 2 * HH,
                                       bar + 2 * 16384);
  // step-invariant attention term (fp32)
  encwe2_k<<<dim3(128, 16), 512, 0, stream>>>(enc_out, attn_w, encWe);

  // persistent decoder: 512 blocks (2 per CU), fp16 weights
  dec_mega9_k<<<512, 1024, 0, stream>>>(gs_emb, encWe, enc_out, aw16, attn_b, attn_v,
                                        w16i0, w16h0, db0, w16i1, w16h1, db1, zeros,
                                        h0_all, h1_all, c1_all, wtd_all, qW_all,
                                        scores_all, bar + 4 * 16384);

  // all logits (h1 slots 1..128), fp16 out_w
  logits3_k<<<dim3(TT, 125), 1024, 0, stream>>>(h1_all + BB * DD, ow16, out_b, out);
}

// Round 12
// 15100.131 us; speedup vs baseline: 4.6913x; 4.6913x over previous
//
#include <hip/hip_runtime.h>

#define BB 16
#define SS 128
#define TT 128
#define EE 512
#define HH 512
#define DD 1024
#define VO 10000

typedef _Float16 half4_t __attribute__((ext_vector_type(4)));
typedef _Float16 half8_t __attribute__((ext_vector_type(8)));

#define FMA4(A, W, X)              \
  A = fmaf((W).x, (X).x, A);       \
  A = fmaf((W).y, (X).y, A);       \
  A = fmaf((W).z, (X).z, A);       \
  A = fmaf((W).w, (X).w, A)

__device__ __forceinline__ float4 h2f4(half4_t h) {
  return make_float4((float)h[0], (float)h[1], (float)h[2], (float)h[3]);
}

__device__ __forceinline__ float wred(float s) {
#pragma unroll
  for (int off = 32; off >= 1; off >>= 1) s += __shfl_xor(s, off, 64);
  return s;
}
__device__ __forceinline__ float sigm(float x) { return 1.f / (1.f + expf(-x)); }

__device__ __forceinline__ void stv(float* p, float v) {
  __hip_atomic_store(p, v, __ATOMIC_RELAXED, __HIP_MEMORY_SCOPE_AGENT);
}

// ---- grid barrier v2: flag-scan, relaxed-only (validated R7-R10) ----
__device__ __forceinline__ void gbar2(unsigned* bar, int lb, int nblk, unsigned target) {
  asm volatile("s_waitcnt vmcnt(0) lgkmcnt(0)" ::: "memory");
  __syncthreads();
  if (threadIdx.x == 0)
    __hip_atomic_store(bar + lb * 16, target, __ATOMIC_RELAXED, __HIP_MEMORY_SCOPE_AGENT);
  if (lb == 0) {
    for (int i = threadIdx.x; i < nblk; i += blockDim.x)
      while (__hip_atomic_load(bar + i * 16, __ATOMIC_RELAXED, __HIP_MEMORY_SCOPE_AGENT) <
             target)
        __builtin_amdgcn_s_sleep(1);
    __syncthreads();
    if (threadIdx.x == 0)
      __hip_atomic_store(bar + 8192, target, __ATOMIC_RELAXED, __HIP_MEMORY_SCOPE_AGENT);
  }
  if (threadIdx.x == 0)
    while (__hip_atomic_load(bar + 8192, __ATOMIC_RELAXED, __HIP_MEMORY_SCOPE_AGENT) <
           target)
      __builtin_amdgcn_s_sleep(1);
  __syncthreads();
}

// ---- fp32 -> fp16 conversion (8 elems/thread) ----
__global__ void f2h_k(const float* __restrict__ src, _Float16* __restrict__ dst, int n8) {
  const int i = blockIdx.x * blockDim.x + threadIdx.x;
  if (i < n8) {
    const float4 a = *(const float4*)&src[i * 8];
    const float4 b = *(const float4*)&src[i * 8 + 4];
    half8_t h;
    h[0] = a.x; h[1] = a.y; h[2] = a.z; h[3] = a.w;
    h[4] = b.x; h[5] = b.y; h[6] = b.z; h[7] = b.w;
    *(half8_t*)&dst[i * 8] = h;
  }
}

// ---- embedding gather (padding_idx=0 -> zeros), out layout [Sn][B][E] ----
__global__ void gather_k(const int* __restrict__ idx, const float* __restrict__ emb,
                         float* __restrict__ out, int Sn) {
  const int s = blockIdx.x, b = blockIdx.y, tid = threadIdx.x;
  const int id = idx[b * Sn + s];
  float4 v = make_float4(0.f, 0.f, 0.f, 0.f);
  if (id != 0) v = ((const float4*)(emb + (size_t)id * EE))[tid];
  ((float4*)(out + ((size_t)s * BB + b) * EE))[tid] = v;
}

// ---- G[z][n][m] = sum_k X[m,k]*W[z,n,k]  (x-part gate GEMMs, float4) ----
template <int K>
__global__ void gemv16b_k(const float* __restrict__ X, int ldx,
                          const float* __restrict__ W, int ldw,
                          float* __restrict__ G, int M, size_t wz, size_t gz) {
  const int lane = threadIdx.x & 63;
  const int n = blockIdx.x * 4 + (threadIdx.x >> 6);
  const int mg = blockIdx.y;
  const int z = blockIdx.z;
  const float* Xr = X + (size_t)mg * 16 * ldx;
  const float* Wn = W + (size_t)z * wz + (size_t)n * ldw;
  float acc[16];
#pragma unroll
  for (int j = 0; j < 16; ++j) acc[j] = 0.f;
#pragma unroll
  for (int it = 0; it < K / 256; ++it) {
    const int k = it * 256 + lane * 4;
    const float4 w4 = *(const float4*)&Wn[k];
#pragma unroll
    for (int j = 0; j < 16; ++j) {
      const float4 xv = *(const float4*)&Xr[(size_t)j * ldx + k];
      FMA4(acc[j], w4, xv);
    }
  }
#pragma unroll
  for (int j = 0; j < 16; ++j) acc[j] = wred(acc[j]);
  float sel = 0.f;
#pragma unroll
  for (int j = 0; j < 16; ++j)
    if (lane == j) sel = acc[j];
  if (lane < 16) G[(size_t)z * gz + (size_t)n * M + mg * 16 + lane] = sel;
}

// ---- persistent encoder: 256 blocks x 512 thr (unchanged from R9) ----
__global__ __launch_bounds__(512, 4) void enc_mega7_k(
    const float* __restrict__ gx, const float* __restrict__ whh,
    const float* __restrict__ bias, float* __restrict__ h_all,
    float* __restrict__ seq, int seq_ts, int seq_bs, unsigned* __restrict__ barbase) {
  const int tid = threadIdx.x, lane = tid & 63, lw = tid >> 6;
  const int dir = blockIdx.x >> 7;
  const int lb = blockIdx.x & 127;
  const int w2 = lb * 8 + lw;
  const int d = w2 >> 1, bq = w2 & 1;
  unsigned* bar = barbase + dir * 16384;

  __shared__ float hs[16][512];

  float wr[4][8];
  const float* wsrc = whh + (size_t)dir * (4 * HH * HH);
#pragma unroll
  for (int g = 0; g < 4; ++g)
#pragma unroll
    for (int j = 0; j < 8; ++j)
      wr[g][j] = wsrc[(size_t)(g * HH + d) * HH + j * 64 + lane];
  float bv[4];
#pragma unroll
  for (int g = 0; g < 4; ++g) bv[g] = bias[dir * 4 * HH + g * HH + d];
  const float* gxz = gx + (size_t)dir * ((size_t)4 * HH * 2048);
  float creg = 0.f;
  unsigned bt = 0;

  for (int t = 0; t < SS; ++t) {
    const int idx = dir ? (SS - 1 - t) : t;
    const float* hp = h_all + ((size_t)t * 2 + dir) * (BB * HH);
    for (int i = tid; i < BB * HH / 4; i += 512)
      *(float4*)&((float*)hs)[i * 4] = *(const float4*)&hp[i * 4];
    __syncthreads();
    float acc[4][8];
#pragma unroll
    for (int g = 0; g < 4; ++g)
#pragma unroll
      for (int j = 0; j < 8; ++j) acc[g][j] = 0.f;
#pragma unroll
    for (int kb = 0; kb < 8; ++kb) {
      const int k = kb * 64 + lane;
#pragma unroll
      for (int j = 0; j < 8; ++j) {
        const float xv = hs[bq * 8 + j][k];
#pragma unroll
        for (int g = 0; g < 4; ++g) acc[g][j] = fmaf(wr[g][kb], xv, acc[g][j]);
      }
    }
#pragma unroll
    for (int g = 0; g < 4; ++g)
#pragma unroll
      for (int j = 0; j < 8; ++j) acc[g][j] = wred(acc[g][j]);
    float s0 = 0.f, s1 = 0.f, s2 = 0.f, s3 = 0.f;
#pragma unroll
    for (int j = 0; j < 8; ++j)
      if (lane == j) { s0 = acc[0][j]; s1 = acc[1][j]; s2 = acc[2][j]; s3 = acc[3][j]; }
    if (lane < 8) {
      const int b = bq * 8 + lane;
      const int m = idx * 16 + b;
      const float gi = sigm(s0 + bv[0] + gxz[(size_t)(0 * HH + d) * 2048 + m]);
      const float gf = sigm(s1 + bv[1] + gxz[(size_t)(1 * HH + d) * 2048 + m]);
      const float gg = tanhf(s2 + bv[2] + gxz[(size_t)(2 * HH + d) * 2048 + m]);
      const float go = sigm(s3 + bv[3] + gxz[(size_t)(3 * HH + d) * 2048 + m]);
      const float cn = gf * creg + gi * gg;
      creg = cn;
      const float hv = go * tanhf(cn);
      stv(h_all + ((size_t)(t + 1) * 2 + dir) * (BB * HH) + b * HH + d, hv);
      seq[(size_t)idx * seq_ts + (size_t)b * seq_bs + dir * HH + d] = hv;
    }
    gbar2(bar, lb, 128, ++bt);
  }
}

// ---- persistent decoder (R9 structure, fp16 weights): 256 blocks x 1024 thr;
// wave = (d, batch-quad) owns all 4 gate rows; direct-global x; 5 barriers/step ----
__global__ __launch_bounds__(1024, 4) void dec_mega7h_k(
    const float* __restrict__ gs_emb, const float* __restrict__ encWe,
    const float* __restrict__ enc_out, const _Float16* __restrict__ aw16,
    const float* __restrict__ attn_b, const float* __restrict__ attn_v,
    const _Float16* __restrict__ w16i0, const _Float16* __restrict__ w16h0,
    const float* __restrict__ b0, const _Float16* __restrict__ w16i1,
    const _Float16* __restrict__ w16h1, const float* __restrict__ b1,
    const float* __restrict__ zeros, float* __restrict__ h0_all,
    float* __restrict__ h1_all, float* __restrict__ c1_all, float* __restrict__ wtd_all,
    float* __restrict__ qW_all, float* __restrict__ scores_all,
    unsigned* __restrict__ bar) {
  const int tid = threadIdx.x, lane = tid & 63, lw = tid >> 6;
  const int blk = blockIdx.x;
  const int w = blk * 16 + lw;  // 0..4095
  const int d = w >> 2, bq = w & 3;
  const int b_att = blk >> 4, shard = blk & 15;

  __shared__ float xch[4][4][16];
  __shared__ float sco[SS];
  __shared__ float sred[16][64];

  const _Float16* w0i0 = w16i0 + (size_t)(0 * DD + d) * 1536;
  const _Float16* w0i1 = w16i0 + (size_t)(1 * DD + d) * 1536;
  const _Float16* w0i2 = w16i0 + (size_t)(2 * DD + d) * 1536;
  const _Float16* w0i3 = w16i0 + (size_t)(3 * DD + d) * 1536;
  const _Float16* w0h0 = w16h0 + (size_t)(0 * DD + d) * 1024;
  const _Float16* w0h1 = w16h0 + (size_t)(1 * DD + d) * 1024;
  const _Float16* w0h2 = w16h0 + (size_t)(2 * DD + d) * 1024;
  const _Float16* w0h3 = w16h0 + (size_t)(3 * DD + d) * 1024;
  const _Float16* w1i0 = w16i1 + (size_t)(0 * DD + d) * 1024;
  const _Float16* w1i1 = w16i1 + (size_t)(1 * DD + d) * 1024;
  const _Float16* w1i2 = w16i1 + (size_t)(2 * DD + d) * 1024;
  const _Float16* w1i3 = w16i1 + (size_t)(3 * DD + d) * 1024;
  const _Float16* w1h0 = w16h1 + (size_t)(0 * DD + d) * 1024;
  const _Float16* w1h1 = w16h1 + (size_t)(1 * DD + d) * 1024;
  const _Float16* w1h2 = w16h1 + (size_t)(2 * DD + d) * 1024;
  const _Float16* w1h3 = w16h1 + (size_t)(3 * DD + d) * 1024;
  float bv0[4], bv1[4];
#pragma unroll
  for (int g = 0; g < 4; ++g) { bv0[g] = b0[g * DD + d]; bv1[g] = b1[g * DD + d]; }
  const float abv = attn_b[d];
  float c0 = 0.f, c1 = 0.f;
  unsigned bt = 0;

  // ---- prime layer 0: zero input & state -> gates = biases ----
  if (lw == ((d & 3) << 2) && lane < 16) {
    // one owner wave per d within the block (bq==0 wave of this d)
  }
  if (bq == 0 && lane < 16) {
    // only one wave per d writes; lane<16 covers all 16 batches
  }
  if (bq == 0 && lane < 16) {
    const float cn = sigm(bv0[0]) * tanhf(bv0[2]);
    c0 = cn;
    stv(h0_all + lane * DD + d, sigm(bv0[3]) * tanhf(cn));
  }
  gbar2(bar, blk, 256, ++bt);
  // ---- prime layer 1: rows w1i . h0_all[0]  (h1prev = 0) ----
  {
    float acc[4][4];
#pragma unroll
    for (int g = 0; g < 4; ++g)
#pragma unroll
      for (int j = 0; j < 4; ++j) acc[g][j] = 0.f;
#pragma unroll
    for (int it = 0; it < 4; ++it) {
      const int k = it * 256 + lane * 4;
      const float4 q0 = h2f4(*(const half4_t*)&w1i0[k]);
      const float4 q1 = h2f4(*(const half4_t*)&w1i1[k]);
      const float4 q2 = h2f4(*(const half4_t*)&w1i2[k]);
      const float4 q3 = h2f4(*(const half4_t*)&w1i3[k]);
#pragma unroll
      for (int j = 0; j < 4; ++j) {
        const float4 xv = *(const float4*)&h0_all[(bq * 4 + j) * DD + k];
        FMA4(acc[0][j], q0, xv);
        FMA4(acc[1][j], q1, xv);
        FMA4(acc[2][j], q2, xv);
        FMA4(acc[3][j], q3, xv);
      }
    }
#pragma unroll
    for (int g = 0; g < 4; ++g)
#pragma unroll
      for (int j = 0; j < 4; ++j) acc[g][j] = wred(acc[g][j]);
    float s[4] = {0.f, 0.f, 0.f, 0.f};
#pragma unroll
    for (int j = 0; j < 4; ++j)
      if (lane == j) { s[0] = acc[0][j]; s[1] = acc[1][j]; s[2] = acc[2][j]; s[3] = acc[3][j]; }
    if (lane < 4) {
      const int b = bq * 4 + lane;
      const float cn = sigm(s[0] + bv1[0]) * tanhf(s[2] + bv1[2]);
      c1 = cn;
      stv(c1_all + b * DD + d, cn);
      stv(h1_all + b * DD + d, sigm(s[3] + bv1[3]) * tanhf(cn));
    }
  }
  gbar2(bar, blk, 256, ++bt);

  for (int t = 0; t < TT; ++t) {
    // ===== qW[b,d] = attn_b[d] + c1[b,:].attn_w[d,:1024]  (fp16 row) =====
    {
      const float* cb = c1_all + (size_t)t * (BB * DD);
      float qa[4] = {0.f, 0.f, 0.f, 0.f};
#pragma unroll
      for (int it = 0; it < 4; ++it) {
        const int k = it * 256 + lane * 4;
        const float4 w4 = h2f4(*(const half4_t*)&aw16[(size_t)d * 2048 + k]);
#pragma unroll
        for (int j = 0; j < 4; ++j) {
          const float4 xv = *(const float4*)&cb[(bq * 4 + j) * DD + k];
          FMA4(qa[j], w4, xv);
        }
      }
#pragma unroll
      for (int j = 0; j < 4; ++j) qa[j] = wred(qa[j]);
      float sel = 0.f;
#pragma unroll
      for (int j = 0; j < 4; ++j)
        if (lane == j) sel = qa[j];
      if (lane < 4)
        stv(qW_all + (size_t)t * (BB * DD) + (bq * 4 + lane) * DD + d, sel + abv);
    }
    gbar2(bar, blk, 256, ++bt);
    // ===== scores[b_att, shard*8+lw] =====
    if (lw < 8) {
      const int s = shard * 8 + lw;
      const float* ew = encWe + ((size_t)(b_att * SS + s)) * DD;
      const float* qb = qW_all + (size_t)t * (BB * DD) + b_att * DD;
      float a = 0.f;
#pragma unroll
      for (int it = 0; it < 4; ++it) {
        const int k = it * 256 + lane * 4;
        const float4 e4 = *(const float4*)&ew[k];
        const float4 q4 = *(const float4*)&qb[k];
        const float4 v4 = *(const float4*)&attn_v[k];
        a += v4.x * tanhf(q4.x + e4.x) + v4.y * tanhf(q4.y + e4.y) +
             v4.z * tanhf(q4.z + e4.z) + v4.w * tanhf(q4.w + e4.w);
      }
      a = wred(a);
      if (lane == 0) stv(scores_all + (size_t)t * (BB * SS) + b_att * SS + s, a);
    }
    gbar2(bar, blk, 256, ++bt);
    // ===== softmax + weighted sum -> wtd_all[t][b_att][shard*64+lane] =====
    {
      if (tid < SS) sco[tid] = scores_all[(size_t)t * (BB * SS) + b_att * SS + tid];
      __syncthreads();
      float m = -1e30f;
      for (int s = 0; s < SS; ++s) m = fmaxf(m, sco[s]);
      __syncthreads();
      if (tid < SS) sco[tid] = expf(sco[tid] - m);
      __syncthreads();
      float sum = 0.f;
      for (int s = 0; s < SS; ++s) sum += sco[s];
      const float inv = 1.f / sum;
      float p = 0.f;
#pragma unroll
      for (int i = 0; i < 8; ++i) {
        const int s = lw * 8 + i;
        p += sco[s] * enc_out[((size_t)(b_att * SS + s)) * DD + shard * 64 + lane];
      }
      sred[lw][lane] = p;
      __syncthreads();
      if (lw == 0) {
        float a2 = 0.f;
#pragma unroll
        for (int i = 0; i < 16; ++i) a2 += sred[i][lane];
        stv(wtd_all + (size_t)t * (BB * DD) + b_att * DD + shard * 64 + lane, a2 * inv);
      }
    }
    gbar2(bar, blk, 256, ++bt);
    // ===== decoder layer 0: K = wtd(1024) | emb(512) | h0prev(1024) =====
    {
      const float* xw = wtd_all + (size_t)t * (BB * DD);
      const float* em = t ? gs_emb + (size_t)(t - 1) * (BB * EE) : zeros;
      const float* hp = h0_all + (size_t)t * (BB * DD);
      float acc[4][4];
#pragma unroll
      for (int g = 0; g < 4; ++g)
#pragma unroll
        for (int j = 0; j < 4; ++j) acc[g][j] = 0.f;
#pragma unroll
      for (int it = 0; it < 4; ++it) {
        const int k = it * 256 + lane * 4;
        const float4 q0 = h2f4(*(const half4_t*)&w0i0[k]);
        const float4 q1 = h2f4(*(const half4_t*)&w0i1[k]);
        const float4 q2 = h2f4(*(const half4_t*)&w0i2[k]);
        const float4 q3 = h2f4(*(const half4_t*)&w0i3[k]);
#pragma unroll
        for (int j = 0; j < 4; ++j) {
          const float4 xv = *(const float4*)&xw[(bq * 4 + j) * DD + k];
          FMA4(acc[0][j], q0, xv);
          FMA4(acc[1][j], q1, xv);
          FMA4(acc[2][j], q2, xv);
          FMA4(acc[3][j], q3, xv);
        }
      }
#pragma unroll
      for (int it = 4; it < 6; ++it) {
        const int k = it * 256 + lane * 4;
        const float4 q0 = h2f4(*(const half4_t*)&w0i0[k]);
        const float4 q1 = h2f4(*(const half4_t*)&w0i1[k]);
        const float4 q2 = h2f4(*(const half4_t*)&w0i2[k]);
        const float4 q3 = h2f4(*(const half4_t*)&w0i3[k]);
#pragma unroll
        for (int j = 0; j < 4; ++j) {
          const float4 xv = *(const float4*)&em[(bq * 4 + j) * EE + (k - 1024)];
          FMA4(acc[0][j], q0, xv);
          FMA4(acc[1][j], q1, xv);
          FMA4(acc[2][j], q2, xv);
          FMA4(acc[3][j], q3, xv);
        }
      }
#pragma unroll
      for (int it = 0; it < 4; ++it) {
        const int k = it * 256 + lane * 4;
        const float4 q0 = h2f4(*(const half4_t*)&w0h0[k]);
        const float4 q1 = h2f4(*(const half4_t*)&w0h1[k]);
        const float4 q2 = h2f4(*(const half4_t*)&w0h2[k]);
        const float4 q3 = h2f4(*(const half4_t*)&w0h3[k]);
#pragma unroll
        for (int j = 0; j < 4; ++j) {
          const float4 xv = *(const float4*)&hp[(bq * 4 + j) * DD + k];
          FMA4(acc[0][j], q0, xv);
          FMA4(acc[1][j], q1, xv);
          FMA4(acc[2][j], q2, xv);
          FMA4(acc[3][j], q3, xv);
        }
      }
#pragma unroll
      for (int g = 0; g < 4; ++g)
#pragma unroll
        for (int j = 0; j < 4; ++j) acc[g][j] = wred(acc[g][j]);
      float s[4] = {0.f, 0.f, 0.f, 0.f};
#pragma unroll
      for (int j = 0; j < 4; ++j)
        if (lane == j) { s[0] = acc[0][j]; s[1] = acc[1][j]; s[2] = acc[2][j]; s[3] = acc[3][j]; }
      if (lane < 4) {
        const int b = bq * 4 + lane;
        const float cn = sigm(s[1] + bv0[1]) * c0 + sigm(s[0] + bv0[0]) * tanhf(s[2] + bv0[2]);
        c0 = cn;
        stv(h0_all + (size_t)(t + 1) * (BB * DD) + b * DD + d,
            sigm(s[3] + bv0[3]) * tanhf(cn));
      }
    }
    gbar2(bar, blk, 256, ++bt);
    // ===== decoder layer 1: K = h0new(1024) | h1prev(1024) =====
    {
      const float* h0 = h0_all + (size_t)(t + 1) * (BB * DD);
      const float* h1p = h1_all + (size_t)t * (BB * DD);
      float acc[4][4];
#pragma unroll
      for (int g = 0; g < 4; ++g)
#pragma unroll
        for (int j = 0; j < 4; ++j) acc[g][j] = 0.f;
#pragma unroll
      for (int it = 0; it < 4; ++it) {
        const int k = it * 256 + lane * 4;
        const float4 q0 = h2f4(*(const half4_t*)&w1i0[k]);
        const float4 q1 = h2f4(*(const half4_t*)&w1i1[k]);
        const float4 q2 = h2f4(*(const half4_t*)&w1i2[k]);
        const float4 q3 = h2f4(*(const half4_t*)&w1i3[k]);
#pragma unroll
        for (int j = 0; j < 4; ++j) {
          const float4 xv = *(const float4*)&h0[(bq * 4 + j) * DD + k];
          FMA4(acc[0][j], q0, xv);
          FMA4(acc[1][j], q1, xv);
          FMA4(acc[2][j], q2, xv);
          FMA4(acc[3][j], q3, xv);
        }
      }
#pragma unroll
      for (int it = 0; it < 4; ++it) {
        const int k = it * 256 + lane * 4;
        const float4 q0 = h2f4(*(const half4_t*)&w1h0[k]);
        const float4 q1 = h2f4(*(const half4_t*)&w1h1[k]);
        const float4 q2 = h2f4(*(const half4_t*)&w1h2[k]);
        const float4 q3 = h2f4(*(const half4_t*)&w1h3[k]);
#pragma unroll
        for (int j = 0; j < 4; ++j) {
          const float4 xv = *(const float4*)&h1p[(bq * 4 + j) * DD + k];
          FMA4(acc[0][j], q0, xv);
          FMA4(acc[1][j], q1, xv);
          FMA4(acc[2][j], q2, xv);
          FMA4(acc[3][j], q3, xv);
        }
      }
#pragma unroll
      for (int g = 0; g < 4; ++g)
#pragma unroll
        for (int j = 0; j < 4; ++j) acc[g][j] = wred(acc[g][j]);
      float s[4] = {0.f, 0.f, 0.f, 0.f};
#pragma unroll
      for (int j = 0; j < 4; ++j)
        if (lane == j) { s[0] = acc[0][j]; s[1] = acc[1][j]; s[2] = acc[2][j]; s[3] = acc[3][j]; }
      if (lane < 4) {
        const int b = bq * 4 + lane;
        const float cn = sigm(s[1] + bv1[1]) * c1 + sigm(s[0] + bv1[0]) * tanhf(s[2] + bv1[2]);
        c1 = cn;
        stv(c1_all + (size_t)(t + 1) * (BB * DD) + b * DD + d, cn);
        stv(h1_all + (size_t)(t + 1) * (BB * DD) + b * DD + d,
            sigm(s[3] + bv1[3]) * tanhf(cn));
      }
    }
    gbar2(bar, blk, 256, ++bt);
  }
}

// ---- encWe[m][n] = sum_k enc_out[m][k]*attn_w[n][1024+k], LDS-staged, float4 ----
__global__ __launch_bounds__(512) void encwe2_k(const float* __restrict__ enc_out,
                                                const float* __restrict__ attn_w,
                                                float* __restrict__ encWe) {
  const int tid = threadIdx.x, lane = tid & 63, lw = tid >> 6;
  const int mg = blockIdx.x;
  const int nq = blockIdx.y;
  __shared__ float xsl[16][1024];
  for (int i = tid; i < 16 * 1024 / 4; i += 512)
    *(float4*)&((float*)xsl)[i * 4] =
        *(const float4*)&enc_out[(size_t)mg * 16 * 1024 + i * 4];
  __syncthreads();
#pragma unroll 1
  for (int nn = 0; nn < 8; ++nn) {
    const int n = nq * 64 + lw * 8 + nn;
    float acc[16];
#pragma unroll
    for (int j = 0; j < 16; ++j) acc[j] = 0.f;
#pragma unroll
    for (int it = 0; it < 4; ++it) {
      const int k = it * 256 + lane * 4;
      const float4 w4 = *(const float4*)&attn_w[(size_t)n * 2048 + 1024 + k];
#pragma unroll
      for (int j = 0; j < 16; ++j) {
        const float4 xv = *(const float4*)&xsl[j][k];
        FMA4(acc[j], w4, xv);
      }
    }
#pragma unroll
    for (int j = 0; j < 16; ++j) acc[j] = wred(acc[j]);
    float sel = 0.f;
#pragma unroll
    for (int j = 0; j < 16; ++j)
      if (lane == j) sel = acc[j];
    if (lane < 16) encWe[((size_t)mg * 16 + lane) * 1024 + n] = sel;
  }
}

// ---- logits (fp32, unchanged): block = (t, 80 o-rows); h1[t] in LDS ----
__global__ __launch_bounds__(1024, 4) void logits2_k(const float* __restrict__ h1all,
                                                     const float* __restrict__ out_w,
                                                     const float* __restrict__ out_b,
                                                     float* __restrict__ out) {
  const int tid = threadIdx.x, lane = tid & 63, lw = tid >> 6;
  const int t = blockIdx.x;
  const int oq = blockIdx.y;  // 0..124
  __shared__ float hs[16][1024];
  const float* h1 = h1all + (size_t)t * (BB * DD);
  for (int i = tid; i < BB * DD / 4; i += 1024)
    *(float4*)&((float*)hs)[i * 4] = *(const float4*)&h1[i * 4];
  __syncthreads();
  const int obase = oq * 80 + lw * 5;
#pragma unroll
  for (int p = 0; p < 3; ++p) {
    const int nr = (p < 2) ? 2 : 1;
    const int o0 = obase + p * 2;
    float accA[16], accB[16];
#pragma unroll
    for (int b = 0; b < 16; ++b) { accA[b] = 0.f; accB[b] = 0.f; }
    const float* wr0 = out_w + (size_t)o0 * DD;
    const float* wr1 = wr0 + DD;
#pragma unroll
    for (int it = 0; it < 4; ++it) {
      const int k = it * 256 + lane * 4;
      const float4 wa = *(const float4*)&wr0[k];
      float4 wb = make_float4(0.f, 0.f, 0.f, 0.f);
      if (nr == 2) wb = *(const float4*)&wr1[k];
#pragma unroll
      for (int b = 0; b < 16; ++b) {
        const float4 xv = *(const float4*)&hs[b][k];
        FMA4(accA[b], wa, xv);
        if (nr == 2) { FMA4(accB[b], wb, xv); }
      }
    }
#pragma unroll
    for (int b = 0; b < 16; ++b) {
      accA[b] = wred(accA[b]);
      if (nr == 2) accB[b] = wred(accB[b]);
    }
    float sA = 0.f, sB = 0.f;
#pragma unroll
    for (int b = 0; b < 16; ++b)
      if (lane == b) { sA = accA[b]; sB = accB[b]; }
    if (lane < 16) {
      out[(size_t)lane * TT * VO + (size_t)t * VO + o0] = sA + out_b[o0];
      if (nr == 2) out[(size_t)lane * TT * VO + (size_t)t * VO + o0 + 1] = sB + out_b[o0 + 1];
    }
  }
}

extern "C" void kernel_launch(void* const* d_in, const int* in_sizes, int n_in,
                              void* d_out, int out_size, void* d_ws, size_t ws_size,
                              hipStream_t stream) {
  const int* x = (const int*)d_in[0];
  const int* gs = (const int*)d_in[1];
  const float* in_emb = (const float*)d_in[2];
  const float* out_emb = (const float*)d_in[3];
  const float* ewih0 = (const float*)d_in[4];
  const float* ewhh0 = (const float*)d_in[5];
  const float* eb0 = (const float*)d_in[6];
  const float* ewih1 = (const float*)d_in[7];
  const float* ewhh1 = (const float*)d_in[8];
  const float* eb1 = (const float*)d_in[9];
  const float* dwih0 = (const float*)d_in[10];
  const float* dwhh0 = (const float*)d_in[11];
  const float* db0 = (const float*)d_in[12];
  const float* dwih1 = (const float*)d_in[13];
  const float* dwhh1 = (const float*)d_in[14];
  const float* db1 = (const float*)d_in[15];
  const float* attn_w = (const float*)d_in[16];
  const float* attn_b = (const float*)d_in[17];
  const float* attn_v = (const float*)d_in[18];
  const float* out_w = (const float*)d_in[19];
  const float* out_b = (const float*)d_in[20];
  float* out = (float*)d_out;

  float* ws = (float*)d_ws;
  size_t off = 0;
  auto alloc = [&](size_t n) { float* p = ws + off; off += n; return p; };
  // ---- memset region: 5 barrier domains + zeros + enc h_all slot-0s ----
  unsigned* bar = (unsigned*)alloc(5 * 16384);  // encL0 d0/d1, encL1 d0/d1, dec
  float* zeros = alloc(BB * DD);
  float* ehA = alloc((size_t)(SS + 1) * 2 * BB * HH);
  float* ehB = alloc(2 * BB * HH);
  const size_t state_n = off;
  alloc((size_t)SS * 2 * BB * HH);  // enc L1 h_all slots 1..128 (contiguous w/ ehB)
  // ---- fp16 weight copies (decoder LSTM + attn_w) ----
  _Float16* w16i0 = (_Float16*)alloc(4096 * 1536 / 2);
  _Float16* w16h0 = (_Float16*)alloc(4096 * 1024 / 2);
  _Float16* w16i1 = (_Float16*)alloc(4096 * 1024 / 2);
  _Float16* w16h1 = (_Float16*)alloc(4096 * 1024 / 2);
  _Float16* aw16 = (_Float16*)alloc(1024 * 2048 / 2);
  // ---- in-kernel write-once / fully-written buffers ----
  float* h0_all = alloc((size_t)(TT + 1) * BB * DD);
  float* h1_all = alloc((size_t)(TT + 1) * BB * DD);
  float* c1_all = alloc((size_t)(TT + 1) * BB * DD);
  float* wtd_all = alloc((size_t)TT * BB * DD);
  float* qW_all = alloc((size_t)TT * BB * DD);
  float* scores_all = alloc((size_t)TT * BB * SS);
  float* xs_emb = alloc((size_t)SS * BB * EE);
  float* gs_emb = alloc((size_t)TT * BB * EE);
  float* l0 = alloc((size_t)SS * BB * (2 * HH));
  float* enc_out = alloc((size_t)BB * SS * (2 * HH));
  float* encWe = alloc((size_t)BB * SS * DD);
  float* gxA = alloc(2ull * 2048ull * 2048ull);
  (void)ws_size; (void)in_sizes; (void)n_in; (void)out_size;

  hipMemsetAsync(d_ws, 0, state_n * sizeof(float), stream);

  // fp16 weight conversion (parallel, independent; ~30us total)
  f2h_k<<<(4096 * 1536 / 8 + 255) / 256, 256, 0, stream>>>(dwih0, w16i0, 4096 * 1536 / 8);
  f2h_k<<<(4096 * 1024 / 8 + 255) / 256, 256, 0, stream>>>(dwhh0, w16h0, 4096 * 1024 / 8);
  f2h_k<<<(4096 * 1024 / 8 + 255) / 256, 256, 0, stream>>>(dwih1, w16i1, 4096 * 1024 / 8);
  f2h_k<<<(4096 * 1024 / 8 + 255) / 256, 256, 0, stream>>>(dwhh1, w16h1, 4096 * 1024 / 8);
  f2h_k<<<(1024 * 2048 / 8 + 255) / 256, 256, 0, stream>>>(attn_w, aw16, 1024 * 2048 / 8);

  gather_k<<<dim3(SS, BB), 128, 0, stream>>>(x, in_emb, xs_emb, SS);
  gather_k<<<dim3(TT, BB), 128, 0, stream>>>(gs, out_emb, gs_emb, TT);

  // encoder layer 0: parallel x-part, then persistent recurrence
  gemv16b_k<EE><<<dim3(512, 128, 2), 256, 0, stream>>>(
      xs_emb, EE, ewih0, EE, gxA, 2048, (size_t)4 * HH * EE, 2048ull * 2048ull);
  enc_mega7_k<<<256, 512, 0, stream>>>(gxA, ewhh0, eb0, ehA, l0, BB * 2 * HH, 2 * HH, bar);
  // encoder layer 1
  gemv16b_k<2 * HH><<<dim3(512, 128, 2), 256, 0, stream>>>(
      l0, 2 * HH, ewih1, 2 * HH, gxA, 2048, (size_t)4 * HH * 2 * HH, 2048ull * 2048ull);
  enc_mega7_k<<<256, 512, 0, stream>>>(gxA, ewhh1, eb1, ehB, enc_out, 2 * HH, SS * 2 * HH,
                                       bar + 2 * 16384);
  // step-invariant attention term (fp32)
  encwe2_k<<<dim3(128, 16), 512, 0, stream>>>(enc_out, attn_w, encWe);

  // persistent decoder (R9 structure, fp16 weight streams)
  dec_mega7h_k<<<256, 1024, 0, stream>>>(gs_emb, encWe, enc_out, aw16, attn_b, attn_v,
                                         w16i0, w16h0, db0, w16i1, w16h1, db1, zeros,
                                         h0_all, h1_all, c1_all, wtd_all, qW_all,
                                         scores_all, bar + 4 * 16384);

  // all logits (h1 slots 1..128), fp32 out_w (unchanged)
  logits2_k<<<dim3(TT, 125), 1024, 0, stream>>>(h1_all + BB * DD, out_w, out_b, out);
}